// Round 5
// baseline (506.895 us; speedup 1.0000x reference)
//
#include <hip/hip_runtime.h>
#include <cstdint>

#define EPS 1e-5f

// ---- workspace layout (bytes) ----
#define A1_OFF   0ull                 // 8192*98 u32 (a1 bitmasks, 16 ch, py*14+px pairs)
#define W2M_OFF  4030464ull           // 32*25 u32
#define W3M_OFF  4033664ull           // 64*25 u32
#define FW1M_OFF 4040064ull           // 128 u64
#define FW2M_OFF 4041088ull           // 128*2 u64
#define FW3M_OFF 4043136ull           // 10*2 u64
#define T1_OFF   4043296ull           // 16 f32
#define T2_OFF   4043360ull           // 32 f32
#define T3_OFF   4043488ull           // 64 f32
#define TC1_OFF  4043744ull           // 128 f32
#define TC2_OFF  4044256ull           // 128 f32
#define BF_OFF   4044768ull           // 4dlt*4kg*64lane uint4 = 16KB (conv1 B-fragments)

using bf16x8 = __attribute__((ext_vector_type(8))) short;
using f32x4  = __attribute__((ext_vector_type(4))) float;

union FragU { unsigned int u[4]; bf16x8 f; };

__device__ inline unsigned short rne_bf16(float f) {
    unsigned int u = __float_as_uint(f);
    return (unsigned short)((u + 0x7FFFu + ((u >> 16) & 1u)) >> 16);
}

// ---------------------------------------------------------------------------
// Setup (grid=5): pack binarized weights to bitmasks, fold bn+bias into
// thresholds, and build conv1 MFMA B-fragments (4 kx-shift variants x 4 kg).
// ---------------------------------------------------------------------------
__global__ void setup_kernel(
    const float* __restrict__ w1, const float* __restrict__ w2,
    const float* __restrict__ w3,
    const float* __restrict__ fw1, const float* __restrict__ fw2,
    const float* __restrict__ fw3,
    const float* __restrict__ b1, const float* __restrict__ g1,
    const float* __restrict__ be1, const float* __restrict__ m1,
    const float* __restrict__ v1,
    const float* __restrict__ b2, const float* __restrict__ g2,
    const float* __restrict__ be2, const float* __restrict__ m2,
    const float* __restrict__ v2,
    const float* __restrict__ b3, const float* __restrict__ g3,
    const float* __restrict__ be3, const float* __restrict__ m3,
    const float* __restrict__ v3,
    const float* __restrict__ fb1, const float* __restrict__ cm1,
    const float* __restrict__ fb2, const float* __restrict__ cm2,
    unsigned int* __restrict__ w2m, unsigned int* __restrict__ w3m,
    unsigned long long* __restrict__ fw1m, unsigned long long* __restrict__ fw2m,
    unsigned long long* __restrict__ fw3m,
    float* __restrict__ t1, float* __restrict__ t2, float* __restrict__ t3,
    float* __restrict__ tc1, float* __restrict__ tc2,
    uint4* __restrict__ bfrag)
{
    const int tid = threadIdx.x;
    const int blk = blockIdx.x;

    if (blk == 0) {
        if (tid < 16) t1[tid] = m1[tid] - be1[tid]*sqrtf(v1[tid]+EPS)/g1[tid] - b1[tid];
        if (tid < 32) t2[tid] = m2[tid] - be2[tid]*sqrtf(v2[tid]+EPS)/g2[tid] - b2[tid];
        if (tid < 64) t3[tid] = m3[tid] - be3[tid]*sqrtf(v3[tid]+EPS)/g3[tid] - b3[tid];
        if (tid < 128) { tc1[tid] = cm1[tid] - fb1[tid]; tc2[tid] = cm2[tid] - fb2[tid]; }
        for (int t = tid; t < 32*25; t += 256) {        // w2: (32,16,5,5)
            int oc = t / 25, pos = t % 25;
            unsigned int mk = 0;
            for (int ic = 0; ic < 16; ++ic)
                if (w2[(oc*16 + ic)*25 + pos] > 0.0f) mk |= 1u << ic;
            w2m[t] = mk;
        }
    } else if (blk == 1) {
        for (int t = tid; t < 64*25; t += 256) {        // w3: (64,32,5,5)
            int oc = t / 25, pos = t % 25;
            unsigned int mk = 0;
            for (int ic = 0; ic < 32; ++ic)
                if (w3[(oc*32 + ic)*25 + pos] > 0.0f) mk |= 1u << ic;
            w3m[t] = mk;
        }
    } else if (blk == 2) {
        for (int t = tid; t < 128; t += 256) {          // fw1: (128,64)
            unsigned long long mk = 0;
            for (int i = 0; i < 64; ++i)
                if (fw1[t*64 + i] > 0.0f) mk |= 1ull << i;
            fw1m[t] = mk;
        }
    } else if (blk == 3) {
        for (int t = tid; t < 128; t += 256) {          // fw2: (128,128)
            unsigned long long lo = 0, hi = 0;
            for (int i = 0; i < 64; ++i) {
                if (fw2[t*128 + i]      > 0.0f) lo |= 1ull << i;
                if (fw2[t*128 + 64 + i] > 0.0f) hi |= 1ull << i;
            }
            fw2m[2*t] = lo; fw2m[2*t+1] = hi;
        }
        if (tid < 10) {                                  // fw3: (10,128)
            unsigned long long lo = 0, hi = 0;
            for (int i = 0; i < 64; ++i) {
                if (fw3[tid*128 + i]      > 0.0f) lo |= 1ull << i;
                if (fw3[tid*128 + 64 + i] > 0.0f) hi |= 1ull << i;
            }
            fw3m[2*tid] = lo; fw3m[2*tid+1] = hi;
        }
    } else {
        // conv1 B-fragments. B-operand of 16x16x32 bf16 MFMA:
        // n = lane&15 (oc), k = (lane>>4)*8 + j; ck = kg*4 + (lane>>4),
        // kx = j - delta.
        if (tid < 64) {
            const int oc = tid & 15, q = tid >> 4;
            for (int d = 0; d < 4; ++d)
                for (int kg = 0; kg < 4; ++kg) {
                    int ck = kg*4 + q;
                    unsigned short s[8];
                    for (int j = 0; j < 8; ++j) {
                        int kx = j - d;
                        unsigned short v = 0;
                        if (ck < 15 && kx >= 0 && kx < 5)
                            v = (w1[oc*75 + ck*5 + kx] > 0.0f) ? 0x3F80 : 0xBF80;
                        s[j] = v;
                    }
                    uint4 o;
                    o.x = (unsigned int)s[0] | ((unsigned int)s[1] << 16);
                    o.y = (unsigned int)s[2] | ((unsigned int)s[3] << 16);
                    o.z = (unsigned int)s[4] | ((unsigned int)s[5] << 16);
                    o.w = (unsigned int)s[6] | ((unsigned int)s[7] << 16);
                    bfrag[(d*4 + kg)*64 + tid] = o;
                }
        }
    }
}

// Rare exact fp64 sign recompute (one copy; called under divergent exec).
__device__ __attribute__((noinline)) int exact_sign(
    const float* __restrict__ x, const float* __restrict__ w1,
    int n, int oc, int py, int px, float thr)
{
    double best = -1e300;
    #pragma unroll 1
    for (int d2 = 0; d2 < 4; ++d2) {
        int oy = 2*py + (d2 >> 1), ox = 2*px + (d2 & 1);
        double s = 0.0;
        #pragma unroll 1
        for (int c2 = 0; c2 < 3; ++c2)
            #pragma unroll 1
            for (int ky2 = 0; ky2 < 5; ++ky2)
                #pragma unroll 1
                for (int kx2 = 0; kx2 < 5; ++kx2) {
                    float wv = w1[oc*75 + c2*25 + ky2*5 + kx2];
                    float xv = x[(size_t)n*3072 + c2*1024 + (oy + ky2)*32 + ox + kx2];
                    s += (wv > 0.0f) ? (double)xv : -(double)xv;
                }
        best = fmax(best, s);
    }
    return best > (double)thr;
}

// ---------------------------------------------------------------------------
// Kernel A (MFMA, multi-image): conv1 + pool + sign -> packed u32 masks.
// 1024 blocks x 256 thr (4 waves); each block processes 8 images,
// software-pipelined (prefetch i+1's x into regs during compute of i).
// Per image: 14 tasks = (oy-tile tt 0/1) x (ox-group g 0..6); wave w takes
// tasks w, w+4, w+8, w+12. Task: A-frag 16 oy-rows x 8 cols from LDS,
// reused by 4 MFMAs with kx-shifted B variants (delta -> ox = 4g+delta).
// bf16 hi+lo passes accumulate fp32; fp64 recompute if |h-thr| < 2e-3.
// LDS rows 32..35 are never written: they feed only discarded C rows
// (tt=1, quad=3 -> oy 28..31), so garbage there is benign.
// ---------------------------------------------------------------------------
__global__ __launch_bounds__(256, 3) void convpool1_kernel(
    const float* __restrict__ x, const float* __restrict__ w1,
    const float* __restrict__ t1, const uint4* __restrict__ bfrag,
    unsigned int* __restrict__ a1u)
{
    __shared__ alignas(16) unsigned short xh[3*36*44];
    __shared__ alignas(16) unsigned short xl[3*36*44];
    __shared__ unsigned short pk16[196];

    const int tid  = threadIdx.x;
    const int lane = tid & 63;
    const int wv   = tid >> 6;        // wave 0..3
    const int quad = lane >> 4;
    const int me   = lane & 15;
    const int n0   = blockIdx.x * 8;

    FragU B[16];
    #pragma unroll
    for (int i = 0; i < 16; ++i)
        *(uint4*)B[i].u = bfrag[i*64 + lane];

    const float thr = t1[me];
    #pragma unroll 1
    for (int i = -1; i < 8; ++i) {
        // ---- prefetch image i+1 into registers ----
        float4 st[3];
        const int more = (i < 7);
        if (more) {
            const float4* xg = (const float4*)(x + (size_t)(n0 + i + 1) * 3072);
            #pragma unroll
            for (int k = 0; k < 3; ++k) st[k] = xg[tid + k*256];
        }

        // ---- compute image i from LDS ----
        if (i >= 0) {
            const int n = n0 + i;
            #pragma unroll 1
            for (int ti = 0; ti < 4; ++ti) {
                const int task = wv + ti*4;
                if (task >= 14) break;                 // wave-uniform
                const int g = task >> 1, tt = task & 1;

                f32x4 acc[4];
                #pragma unroll
                for (int d = 0; d < 4; ++d) acc[d] = (f32x4){0.f, 0.f, 0.f, 0.f};

                #pragma unroll
                for (int kg = 0; kg < 4; ++kg) {
                    int ck = kg*4 + quad;
                    int ckc = ck < 15 ? ck : 14;       // ck==15 -> zero B
                    int c = ckc / 5, ky = ckc % 5;
                    int idx = (c*36 + ky + me + tt*16)*44 + 4*g;
                    FragU ah, al;
                    uint2 p0 = *(const uint2*)&xh[idx];
                    uint2 p1 = *(const uint2*)&xh[idx + 4];
                    ah.u[0] = p0.x; ah.u[1] = p0.y; ah.u[2] = p1.x; ah.u[3] = p1.y;
                    uint2 q0 = *(const uint2*)&xl[idx];
                    uint2 q1 = *(const uint2*)&xl[idx + 4];
                    al.u[0] = q0.x; al.u[1] = q0.y; al.u[2] = q1.x; al.u[3] = q1.y;
                    #pragma unroll
                    for (int d = 0; d < 4; ++d)
                        acc[d] = __builtin_amdgcn_mfma_f32_16x16x32_bf16(
                            ah.f, B[d*4 + kg].f, acc[d], 0, 0, 0);
                    #pragma unroll
                    for (int d = 0; d < 4; ++d)
                        acc[d] = __builtin_amdgcn_mfma_f32_16x16x32_bf16(
                            al.f, B[d*4 + kg].f, acc[d], 0, 0, 0);
                }

                // pool + sign + pack. Lane holds oc=me, oy = tt*16+quad*4+reg.
                const int valid = !(tt == 1 && quad == 3);
                #pragma unroll
                for (int dp = 0; dp < 2; ++dp) {
                    f32x4 A0 = acc[2*dp], A1 = acc[2*dp + 1];
                    #pragma unroll
                    for (int r = 0; r < 2; ++r) {
                        float h = fmaxf(fmaxf(A0[2*r], A0[2*r+1]),
                                        fmaxf(A1[2*r], A1[2*r+1]));
                        int bit = h > thr;
                        if (valid && fabsf(h - thr) < 2e-3f)
                            bit = exact_sign(x, w1, n, me,
                                             tt*8 + quad*2 + r, 2*g + dp, thr);
                        unsigned long long mk = __ballot(bit);
                        if (me == 0 && valid)
                            pk16[(tt*8 + quad*2 + r)*14 + 2*g + dp] =
                                (unsigned short)(mk >> (quad*16));
                    }
                }
            }
        }
        __syncthreads();

        // ---- output masks for image i; store prefetched image i+1 ----
        if (i >= 0 && tid < 98)
            a1u[(size_t)(n0 + i)*98 + tid] =
                (unsigned int)pk16[2*tid] | ((unsigned int)pk16[2*tid + 1] << 16);
        if (more) {
            #pragma unroll
            for (int k = 0; k < 3; ++k) {
                float4 v = st[k];
                int j = tid + k*256;
                int c = j >> 8, f = j & 255, row = f >> 3, q = f & 7;
                int e = (c*36 + row)*44 + 4*q;
                unsigned short h0 = rne_bf16(v.x), h1 = rne_bf16(v.y),
                               h2 = rne_bf16(v.z), h3 = rne_bf16(v.w);
                float r0 = v.x - __uint_as_float((unsigned int)h0 << 16);
                float r1 = v.y - __uint_as_float((unsigned int)h1 << 16);
                float r2 = v.z - __uint_as_float((unsigned int)h2 << 16);
                float r3 = v.w - __uint_as_float((unsigned int)h3 << 16);
                uint2 ph, pl;
                ph.x = (unsigned int)h0 | ((unsigned int)h1 << 16);
                ph.y = (unsigned int)h2 | ((unsigned int)h3 << 16);
                pl.x = (unsigned int)rne_bf16(r0) | ((unsigned int)rne_bf16(r1) << 16);
                pl.y = (unsigned int)rne_bf16(r2) | ((unsigned int)rne_bf16(r3) << 16);
                *(uint2*)&xh[e] = ph;
                *(uint2*)&xl[e] = pl;
            }
        }
        __syncthreads();
    }
}

// ---------------------------------------------------------------------------
// Kernel B (fused): conv2 (xor/popc, pair-packed taps) + pool + sign -> LDS
// masks, then conv3+fc1+fc2+fc3+log_softmax. 256 blocks x 256 thr; each
// block: 32 images in 4 sub-batches of 8. No global a2 round-trip.
// ---------------------------------------------------------------------------
__global__ __launch_bounds__(256) void conv2tail_kernel(
    const unsigned int* __restrict__ a1u, const unsigned int* __restrict__ w2m,
    const float* __restrict__ t2,
    const unsigned int* __restrict__ w3m, const float* __restrict__ t3,
    const unsigned long long* __restrict__ fw1m, const float* __restrict__ tc1,
    const unsigned long long* __restrict__ fw2m, const float* __restrict__ tc2,
    const unsigned long long* __restrict__ fw3m,
    const float* __restrict__ cm3, const float* __restrict__ cv3,
    float* __restrict__ out)
{
    __shared__ unsigned int M[8][14][16];
    __shared__ unsigned int P[8][14][16];
    __shared__ unsigned int Q[8][13][16];
    __shared__ unsigned int a2l[8][25];
    __shared__ unsigned int w3s[1600];
    __shared__ unsigned long long fw1s[128], fw2s[256], fw3s[20];  // fw3: 10 rows x 2 u64
    __shared__ float t3s[64], tc1s[128], tc2s[128], cm3s[16], cv3s[16];

    const int tid = threadIdx.x;
    const int lane = tid & 63;
    const int wv = tid >> 6;

    // ---- stage tail weights (once per block) ----
    for (int i = tid; i < 1600; i += 256) w3s[i] = w3m[i];
    if (tid < 128) { fw1s[tid] = fw1m[tid]; tc1s[tid] = tc1[tid]; tc2s[tid] = tc2[tid]; }
    fw2s[tid] = fw2m[tid];
    if (tid < 20) fw3s[tid] = fw3m[tid];
    if (tid < 64) t3s[tid] = t3[tid];
    if (tid < 10) { cm3s[tid] = cm3[tid]; cv3s[tid] = cv3[tid]; }

    // conv2 weights (oc fixed per thread)
    const int img = tid >> 5, oc = tid & 31;
    unsigned int wrow[25];
    #pragma unroll
    for (int k = 0; k < 25; ++k) wrow[k] = w2m[oc*25 + k];
    unsigned int wp[5][2], wc0, wc1, wcs;
    #pragma unroll
    for (int ky = 0; ky < 5; ++ky) {
        wp[ky][0] = wrow[ky*5]     | (wrow[ky*5+1] << 16);
        wp[ky][1] = wrow[ky*5 + 2] | (wrow[ky*5+3] << 16);
    }
    wc0 = wrow[4]  | (wrow[9]  << 16);
    wc1 = wrow[14] | (wrow[19] << 16);
    wcs = wrow[24];
    const float thr = t2[oc];

    #pragma unroll 1
    for (int sb = 0; sb < 4; ++sb) {
        const int n0 = blockIdx.x*32 + sb*8;
        __syncthreads();                 // prev sub-batch fully consumed

        // ---- stage a1 masks ----
        for (int i = tid; i < 8*98; i += 256) {
            unsigned int v = a1u[(size_t)n0*98 + i];
            int e = 2*i;
            int im = e / 196, r = e - im*196;
            int y0 = r / 14, c0 = r - y0*14;
            int r1 = r + 1, y1 = r1 / 14, c1 = r1 - y1*14;
            M[im][y0][c0] = v & 0xffffu;
            M[im][y1][c1] = v >> 16;
        }
        __syncthreads();
        for (int i = tid; i < 8*14*13; i += 256) {
            int im = i / 182, r = i - im*182, y = r / 13, j = r - y*13;
            P[im][y][j] = M[im][y][j] | (M[im][y][j+1] << 16);
        }
        for (int i = tid; i < 8*13*14; i += 256) {
            int im = i / 182, r = i - im*182, y = r / 14, j = r - y*14;
            Q[im][y][j] = M[im][y][j] | (M[im][y+1][j] << 16);
        }
        __syncthreads();

        // ---- conv2 + pool + sign ----
        unsigned int bits = 0;
        int hprev[5];
        #pragma unroll 2
        for (int oy = 0; oy < 10; ++oy) {
            unsigned int Pr[5][12];
            #pragma unroll
            for (int ky = 0; ky < 5; ++ky) {
                const uint4* pr = (const uint4*)&P[img][oy + ky][0];
                uint4 a = pr[0], b = pr[1], c = pr[2];
                Pr[ky][0]=a.x; Pr[ky][1]=a.y; Pr[ky][2]=a.z; Pr[ky][3]=a.w;
                Pr[ky][4]=b.x; Pr[ky][5]=b.y; Pr[ky][6]=b.z; Pr[ky][7]=b.w;
                Pr[ky][8]=c.x; Pr[ky][9]=c.y; Pr[ky][10]=c.z; Pr[ky][11]=c.w;
            }
            unsigned int Qa[10], Qb[10], Ms[10];
            {
                const uint4* qa = (const uint4*)&Q[img][oy][4];
                const uint2* qa2 = (const uint2*)&Q[img][oy][12];
                uint4 a = qa[0], b = qa[1]; uint2 c = qa2[0];
                Qa[0]=a.x; Qa[1]=a.y; Qa[2]=a.z; Qa[3]=a.w;
                Qa[4]=b.x; Qa[5]=b.y; Qa[6]=b.z; Qa[7]=b.w; Qa[8]=c.x; Qa[9]=c.y;
                const uint4* qb = (const uint4*)&Q[img][oy+2][4];
                const uint2* qb2 = (const uint2*)&Q[img][oy+2][12];
                uint4 d = qb[0], e = qb[1]; uint2 f = qb2[0];
                Qb[0]=d.x; Qb[1]=d.y; Qb[2]=d.z; Qb[3]=d.w;
                Qb[4]=e.x; Qb[5]=e.y; Qb[6]=e.z; Qb[7]=e.w; Qb[8]=f.x; Qb[9]=f.y;
                const uint4* ms = (const uint4*)&M[img][oy+4][4];
                const uint2* ms2 = (const uint2*)&M[img][oy+4][12];
                uint4 g = ms[0], h = ms[1]; uint2 k2 = ms2[0];
                Ms[0]=g.x; Ms[1]=g.y; Ms[2]=g.z; Ms[3]=g.w;
                Ms[4]=h.x; Ms[5]=h.y; Ms[6]=h.z; Ms[7]=h.w; Ms[8]=k2.x; Ms[9]=k2.y;
            }
            int X[10];
            #pragma unroll
            for (int ox = 0; ox < 10; ++ox) {
                int s = 0;
                #pragma unroll
                for (int ky = 0; ky < 5; ++ky)
                    s += __popc(Pr[ky][ox] ^ wp[ky][0]) + __popc(Pr[ky][ox+2] ^ wp[ky][1]);
                s += __popc(Qa[ox] ^ wc0) + __popc(Qb[ox] ^ wc1) + __popc(Ms[ox] ^ wcs);
                X[ox] = s;
            }
            #pragma unroll
            for (int px = 0; px < 5; ++px) {
                int h = min(X[2*px], X[2*px+1]);
                if ((oy & 1) == 0) hprev[px] = h;
                else {
                    int mn = min(hprev[px], h);
                    if ((float)(400 - 2*mn) > thr) bits |= 1u << ((oy >> 1)*5 + px);
                }
            }
        }
        #pragma unroll
        for (int cell = 0; cell < 25; ++cell) {
            unsigned long long m = __ballot((bits >> cell) & 1);
            if (lane == 0)  a2l[2*wv][cell]     = (unsigned int)m;
            if (lane == 32) a2l[2*wv + 1][cell] = (unsigned int)(m >> 32);
        }
        __syncthreads();

        // ---- tail: 2 rounds x 4 waves = 8 images ----
        #pragma unroll 1
        for (int rnd = 0; rnd < 2; ++rnd) {
            const int im = wv + 4*rnd;
            const int n = n0 + im;

            unsigned int av[25];
            #pragma unroll
            for (int k = 0; k < 25; ++k) av[k] = a2l[im][k];

            int X = 0;
            #pragma unroll
            for (int k = 0; k < 25; ++k) X += __popc(av[k] ^ w3s[lane*25 + k]);
            float d3 = (float)(800 - 2*X);
            unsigned long long a3 = __ballot(d3 > t3s[lane]);

            int o1 = lane + 64;
            int d0 = 64 - 2*(int)__popcll(a3 ^ fw1s[lane]);
            int d1 = 64 - 2*(int)__popcll(a3 ^ fw1s[o1]);
            unsigned long long a4lo = __ballot((float)d0 > tc1s[lane]);
            unsigned long long a4hi = __ballot((float)d1 > tc1s[o1]);

            int e0 = 128 - 2*(int)(__popcll(a4lo ^ fw2s[2*lane]) + __popcll(a4hi ^ fw2s[2*lane+1]));
            int e1 = 128 - 2*(int)(__popcll(a4lo ^ fw2s[2*o1])   + __popcll(a4hi ^ fw2s[2*o1+1]));
            unsigned long long a5lo = __ballot((float)e0 > tc2s[lane]);
            unsigned long long a5hi = __ballot((float)e1 > tc2s[o1]);

            float y = -1e30f;
            if (lane < 10) {
                int f = 128 - 2*(int)(__popcll(a5lo ^ fw3s[2*lane]) + __popcll(a5hi ^ fw3s[2*lane+1]));
                y = ((float)f - cm3s[lane]) / sqrtf(cv3s[lane] + EPS);
            }
            float mx = y;
            #pragma unroll
            for (int off = 8; off > 0; off >>= 1) mx = fmaxf(mx, __shfl_xor(mx, off, 16));
            float s = (lane < 10) ? expf(y - mx) : 0.0f;
            #pragma unroll
            for (int off = 8; off > 0; off >>= 1) s += __shfl_xor(s, off, 16);
            if (lane < 10) out[(size_t)n*10 + lane] = y - mx - logf(s);
        }
    }
}

// ---------------------------------------------------------------------------
extern "C" void kernel_launch(void* const* d_in, const int* in_sizes, int n_in,
                              void* d_out, int out_size, void* d_ws, size_t ws_size,
                              hipStream_t stream)
{
    const float* x   = (const float*)d_in[0];
    const float* w1  = (const float*)d_in[1];
    const float* b1  = (const float*)d_in[2];
    const float* g1  = (const float*)d_in[3];
    const float* be1 = (const float*)d_in[4];
    const float* m1  = (const float*)d_in[5];
    const float* v1  = (const float*)d_in[6];
    const float* w2  = (const float*)d_in[7];
    const float* b2  = (const float*)d_in[8];
    const float* g2  = (const float*)d_in[9];
    const float* be2 = (const float*)d_in[10];
    const float* m2  = (const float*)d_in[11];
    const float* v2  = (const float*)d_in[12];
    const float* w3  = (const float*)d_in[13];
    const float* b3  = (const float*)d_in[14];
    const float* g3  = (const float*)d_in[15];
    const float* be3 = (const float*)d_in[16];
    const float* m3  = (const float*)d_in[17];
    const float* v3  = (const float*)d_in[18];
    const float* fw1 = (const float*)d_in[19];
    const float* fb1 = (const float*)d_in[20];
    const float* cm1 = (const float*)d_in[21];
    const float* fw2 = (const float*)d_in[23];
    const float* fb2 = (const float*)d_in[24];
    const float* cm2 = (const float*)d_in[25];
    const float* fw3 = (const float*)d_in[27];
    const float* cm3 = (const float*)d_in[28];
    const float* cv3 = (const float*)d_in[29];

    char* ws = (char*)d_ws;
    unsigned int*       a1u  = (unsigned int*)(ws + A1_OFF);
    unsigned int*       w2m  = (unsigned int*)(ws + W2M_OFF);
    unsigned int*       w3m  = (unsigned int*)(ws + W3M_OFF);
    unsigned long long* fw1m = (unsigned long long*)(ws + FW1M_OFF);
    unsigned long long* fw2m = (unsigned long long*)(ws + FW2M_OFF);
    unsigned long long* fw3m = (unsigned long long*)(ws + FW3M_OFF);
    float* t1  = (float*)(ws + T1_OFF);
    float* t2  = (float*)(ws + T2_OFF);
    float* t3  = (float*)(ws + T3_OFF);
    float* tc1 = (float*)(ws + TC1_OFF);
    float* tc2 = (float*)(ws + TC2_OFF);
    uint4* bfrag = (uint4*)(ws + BF_OFF);

    setup_kernel<<<5, 256, 0, stream>>>(
        w1, w2, w3, fw1, fw2, fw3,
        b1, g1, be1, m1, v1,
        b2, g2, be2, m2, v2,
        b3, g3, be3, m3, v3,
        fb1, cm1, fb2, cm2,
        w2m, w3m, fw1m, fw2m, fw3m, t1, t2, t3, tc1, tc2, bfrag);

    convpool1_kernel<<<1024, 256, 0, stream>>>(x, w1, t1, bfrag, a1u);
    conv2tail_kernel<<<256, 256, 0, stream>>>(a1u, w2m, t2, w3m, t3,
                                              fw1m, tc1, fw2m, tc2, fw3m,
                                              cm3, cv3, (float*)d_out);
}

// Round 6
// 342.579 us; speedup vs baseline: 1.4796x; 1.4796x over previous
//
#include <hip/hip_runtime.h>
#include <cstdint>

#define EPS 1e-5f

// ---- workspace layout (bytes) ----
#define A1_OFF   0ull                 // 8192*98 u32 (a1 bitmasks, 16 ch, py*14+px pairs)
#define W2M_OFF  4030464ull           // 32*25 u32
#define W3M_OFF  4033664ull           // 64*25 u32
#define FW1M_OFF 4040064ull           // 128 u64
#define FW2M_OFF 4041088ull           // 128*2 u64
#define FW3M_OFF 4043136ull           // 10*2 u64
#define T1_OFF   4043296ull           // 16 f32
#define T2_OFF   4043360ull           // 32 f32
#define T3_OFF   4043488ull           // 64 f32
#define TC1_OFF  4043744ull           // 128 f32
#define TC2_OFF  4044256ull           // 128 f32
#define BF_OFF   4044768ull           // 4dlt*4kg*64lane uint4 = 16KB (conv1 B-fragments)
#define FIXCNT_OFF 4061184ull         // 1 u32
#define FIXREC_OFF 4061248ull         // 32768 uint2 = 256KB
#define FIXCAP   32768u

using bf16x8 = __attribute__((ext_vector_type(8))) short;
using f32x4  = __attribute__((ext_vector_type(4))) float;

union FragU { unsigned int u[4]; bf16x8 f; };

__device__ inline unsigned short rne_bf16(float f) {
    unsigned int u = __float_as_uint(f);
    return (unsigned short)((u + 0x7FFFu + ((u >> 16) & 1u)) >> 16);
}

// ---------------------------------------------------------------------------
// Setup (grid=5): pack binarized weights to bitmasks, fold bn+bias into
// thresholds, build conv1 MFMA B-fragments, zero the fixup counter.
// ---------------------------------------------------------------------------
__global__ void setup_kernel(
    const float* __restrict__ w1, const float* __restrict__ w2,
    const float* __restrict__ w3,
    const float* __restrict__ fw1, const float* __restrict__ fw2,
    const float* __restrict__ fw3,
    const float* __restrict__ b1, const float* __restrict__ g1,
    const float* __restrict__ be1, const float* __restrict__ m1,
    const float* __restrict__ v1,
    const float* __restrict__ b2, const float* __restrict__ g2,
    const float* __restrict__ be2, const float* __restrict__ m2,
    const float* __restrict__ v2,
    const float* __restrict__ b3, const float* __restrict__ g3,
    const float* __restrict__ be3, const float* __restrict__ m3,
    const float* __restrict__ v3,
    const float* __restrict__ fb1, const float* __restrict__ cm1,
    const float* __restrict__ fb2, const float* __restrict__ cm2,
    unsigned int* __restrict__ w2m, unsigned int* __restrict__ w3m,
    unsigned long long* __restrict__ fw1m, unsigned long long* __restrict__ fw2m,
    unsigned long long* __restrict__ fw3m,
    float* __restrict__ t1, float* __restrict__ t2, float* __restrict__ t3,
    float* __restrict__ tc1, float* __restrict__ tc2,
    uint4* __restrict__ bfrag, unsigned int* __restrict__ fixcnt)
{
    const int tid = threadIdx.x;
    const int blk = blockIdx.x;

    if (blk == 0) {
        if (tid < 16) t1[tid] = m1[tid] - be1[tid]*sqrtf(v1[tid]+EPS)/g1[tid] - b1[tid];
        if (tid < 32) t2[tid] = m2[tid] - be2[tid]*sqrtf(v2[tid]+EPS)/g2[tid] - b2[tid];
        if (tid < 64) t3[tid] = m3[tid] - be3[tid]*sqrtf(v3[tid]+EPS)/g3[tid] - b3[tid];
        if (tid < 128) { tc1[tid] = cm1[tid] - fb1[tid]; tc2[tid] = cm2[tid] - fb2[tid]; }
        for (int t = tid; t < 32*25; t += 256) {        // w2: (32,16,5,5)
            int oc = t / 25, pos = t % 25;
            unsigned int mk = 0;
            for (int ic = 0; ic < 16; ++ic)
                if (w2[(oc*16 + ic)*25 + pos] > 0.0f) mk |= 1u << ic;
            w2m[t] = mk;
        }
    } else if (blk == 1) {
        for (int t = tid; t < 64*25; t += 256) {        // w3: (64,32,5,5)
            int oc = t / 25, pos = t % 25;
            unsigned int mk = 0;
            for (int ic = 0; ic < 32; ++ic)
                if (w3[(oc*32 + ic)*25 + pos] > 0.0f) mk |= 1u << ic;
            w3m[t] = mk;
        }
    } else if (blk == 2) {
        for (int t = tid; t < 128; t += 256) {          // fw1: (128,64)
            unsigned long long mk = 0;
            for (int i = 0; i < 64; ++i)
                if (fw1[t*64 + i] > 0.0f) mk |= 1ull << i;
            fw1m[t] = mk;
        }
    } else if (blk == 3) {
        for (int t = tid; t < 128; t += 256) {          // fw2: (128,128)
            unsigned long long lo = 0, hi = 0;
            for (int i = 0; i < 64; ++i) {
                if (fw2[t*128 + i]      > 0.0f) lo |= 1ull << i;
                if (fw2[t*128 + 64 + i] > 0.0f) hi |= 1ull << i;
            }
            fw2m[2*t] = lo; fw2m[2*t+1] = hi;
        }
        if (tid < 10) {                                  // fw3: (10,128)
            unsigned long long lo = 0, hi = 0;
            for (int i = 0; i < 64; ++i) {
                if (fw3[tid*128 + i]      > 0.0f) lo |= 1ull << i;
                if (fw3[tid*128 + 64 + i] > 0.0f) hi |= 1ull << i;
            }
            fw3m[2*tid] = lo; fw3m[2*tid+1] = hi;
        }
    } else {
        if (tid == 0) fixcnt[0] = 0;
        // conv1 B-fragments. B-operand of 16x16x32 bf16 MFMA:
        // n = lane&15 (oc), k = (lane>>4)*8 + j; ck = kg*4 + (lane>>4),
        // kx = j - delta.
        if (tid < 64) {
            const int oc = tid & 15, q = tid >> 4;
            for (int d = 0; d < 4; ++d)
                for (int kg = 0; kg < 4; ++kg) {
                    int ck = kg*4 + q;
                    unsigned short s[8];
                    for (int j = 0; j < 8; ++j) {
                        int kx = j - d;
                        unsigned short v = 0;
                        if (ck < 15 && kx >= 0 && kx < 5)
                            v = (w1[oc*75 + ck*5 + kx] > 0.0f) ? 0x3F80 : 0xBF80;
                        s[j] = v;
                    }
                    uint4 o;
                    o.x = (unsigned int)s[0] | ((unsigned int)s[1] << 16);
                    o.y = (unsigned int)s[2] | ((unsigned int)s[3] << 16);
                    o.z = (unsigned int)s[4] | ((unsigned int)s[5] << 16);
                    o.w = (unsigned int)s[6] | ((unsigned int)s[7] << 16);
                    bfrag[(d*4 + kg)*64 + tid] = o;
                }
        }
    }
}

// ---------------------------------------------------------------------------
// Kernel A (MFMA, multi-image): conv1 + pool + sign -> packed u32 masks.
// 1024 blocks x 256 thr (4 waves); each block processes 8 images,
// software-pipelined (prefetch i+1's x into regs during compute of i).
// Per image: 14 tasks = (ox-group g 0..6) x (oy-tile tt 0/1); wave w takes
// tasks w, w+4, w+8, w+12. Task: A-frag 16 oy-rows x 8 cols from LDS,
// reused by 4 MFMAs with kx-shifted B variants (delta -> ox = 4g+delta).
// bf16 hi+lo passes accumulate fp32. Near-threshold cells (|h-thr|<2e-3)
// are appended to a global fixup list; NO function calls in the hot loop
// (a noinline call here previously forced the 64-VGPR B array to spill
// to scratch -> 10x slowdown, R3-R5).
// ---------------------------------------------------------------------------
__global__ __launch_bounds__(256, 3) void convpool1_kernel(
    const float* __restrict__ x, const float* __restrict__ t1,
    const uint4* __restrict__ bfrag, unsigned int* __restrict__ a1u,
    unsigned int* __restrict__ fixcnt, uint2* __restrict__ fixrec)
{
    __shared__ alignas(16) unsigned short xh[3*36*44];
    __shared__ alignas(16) unsigned short xl[3*36*44];
    __shared__ unsigned short pk16[196];

    const int tid  = threadIdx.x;
    const int lane = tid & 63;
    const int wv   = tid >> 6;        // wave 0..3
    const int quad = lane >> 4;
    const int me   = lane & 15;
    const int n0   = blockIdx.x * 8;

    FragU B[16];
    #pragma unroll
    for (int i = 0; i < 16; ++i)
        *(uint4*)B[i].u = bfrag[i*64 + lane];

    const float thr = t1[me];
    #pragma unroll 1
    for (int i = -1; i < 8; ++i) {
        // ---- prefetch image i+1 into registers ----
        float4 st[3];
        const int more = (i < 7);
        if (more) {
            const float4* xg = (const float4*)(x + (size_t)(n0 + i + 1) * 3072);
            #pragma unroll
            for (int k = 0; k < 3; ++k) st[k] = xg[tid + k*256];
        }

        // ---- compute image i from LDS ----
        if (i >= 0) {
            const int n = n0 + i;
            #pragma unroll 1
            for (int ti = 0; ti < 4; ++ti) {
                const int task = wv + ti*4;
                if (task >= 14) break;                 // wave-uniform
                const int g = task >> 1, tt = task & 1;

                f32x4 acc[4];
                #pragma unroll
                for (int d = 0; d < 4; ++d) acc[d] = (f32x4){0.f, 0.f, 0.f, 0.f};

                #pragma unroll
                for (int kg = 0; kg < 4; ++kg) {
                    int ck = kg*4 + quad;
                    int ckc = ck < 15 ? ck : 14;       // ck==15 -> zero B
                    int c = ckc / 5, ky = ckc % 5;
                    int idx = (c*36 + ky + me + tt*16)*44 + 4*g;
                    FragU ah, al;
                    uint2 p0 = *(const uint2*)&xh[idx];
                    uint2 p1 = *(const uint2*)&xh[idx + 4];
                    ah.u[0] = p0.x; ah.u[1] = p0.y; ah.u[2] = p1.x; ah.u[3] = p1.y;
                    uint2 q0 = *(const uint2*)&xl[idx];
                    uint2 q1 = *(const uint2*)&xl[idx + 4];
                    al.u[0] = q0.x; al.u[1] = q0.y; al.u[2] = q1.x; al.u[3] = q1.y;
                    #pragma unroll
                    for (int d = 0; d < 4; ++d)
                        acc[d] = __builtin_amdgcn_mfma_f32_16x16x32_bf16(
                            ah.f, B[d*4 + kg].f, acc[d], 0, 0, 0);
                    #pragma unroll
                    for (int d = 0; d < 4; ++d)
                        acc[d] = __builtin_amdgcn_mfma_f32_16x16x32_bf16(
                            al.f, B[d*4 + kg].f, acc[d], 0, 0, 0);
                }

                // pool + sign + pack. Lane holds oc=me, oy = tt*16+quad*4+reg.
                const int valid = !(tt == 1 && quad == 3);
                #pragma unroll
                for (int dp = 0; dp < 2; ++dp) {
                    f32x4 A0 = acc[2*dp], A1 = acc[2*dp + 1];
                    #pragma unroll
                    for (int r = 0; r < 2; ++r) {
                        float h = fmaxf(fmaxf(A0[2*r], A0[2*r+1]),
                                        fmaxf(A1[2*r], A1[2*r+1]));
                        int bit = h > thr;
                        if (valid && fabsf(h - thr) < 2e-3f) {
                            // rare: defer exact decision to fixup kernel
                            int cell = (tt*8 + quad*2 + r)*14 + 2*g + dp;
                            unsigned int slot = atomicAdd(fixcnt, 1u);
                            if (slot < FIXCAP) {
                                uint2 rec;
                                rec.x = (unsigned int)n;
                                rec.y = ((unsigned int)cell << 8) | (unsigned int)me;
                                fixrec[slot] = rec;
                            }
                        }
                        unsigned long long mk = __ballot(bit);
                        if (me == 0 && valid)
                            pk16[(tt*8 + quad*2 + r)*14 + 2*g + dp] =
                                (unsigned short)(mk >> (quad*16));
                    }
                }
            }
        }
        __syncthreads();

        // ---- output masks for image i; store prefetched image i+1 ----
        if (i >= 0 && tid < 98)
            a1u[(size_t)(n0 + i)*98 + tid] =
                (unsigned int)pk16[2*tid] | ((unsigned int)pk16[2*tid + 1] << 16);
        if (more) {
            #pragma unroll
            for (int k = 0; k < 3; ++k) {
                float4 v = st[k];
                int j = tid + k*256;
                int c = j >> 8, f = j & 255, row = f >> 3, q = f & 7;
                int e = (c*36 + row)*44 + 4*q;
                unsigned short h0 = rne_bf16(v.x), h1 = rne_bf16(v.y),
                               h2 = rne_bf16(v.z), h3 = rne_bf16(v.w);
                float r0 = v.x - __uint_as_float((unsigned int)h0 << 16);
                float r1 = v.y - __uint_as_float((unsigned int)h1 << 16);
                float r2 = v.z - __uint_as_float((unsigned int)h2 << 16);
                float r3 = v.w - __uint_as_float((unsigned int)h3 << 16);
                uint2 ph, pl;
                ph.x = (unsigned int)h0 | ((unsigned int)h1 << 16);
                ph.y = (unsigned int)h2 | ((unsigned int)h3 << 16);
                pl.x = (unsigned int)rne_bf16(r0) | ((unsigned int)rne_bf16(r1) << 16);
                pl.y = (unsigned int)rne_bf16(r2) | ((unsigned int)rne_bf16(r3) << 16);
                *(uint2*)&xh[e] = ph;
                *(uint2*)&xl[e] = pl;
            }
        }
        __syncthreads();
    }
}

// ---------------------------------------------------------------------------
// Fixup: exact fp64 recompute of near-threshold pooled cells; patch a1u bits.
// ---------------------------------------------------------------------------
__global__ void fixup_kernel(
    const float* __restrict__ x, const float* __restrict__ w1,
    const float* __restrict__ t1,
    const unsigned int* __restrict__ fixcnt, const uint2* __restrict__ fixrec,
    unsigned int* __restrict__ a1u)
{
    unsigned int cnt = fixcnt[0];
    if (cnt > FIXCAP) cnt = FIXCAP;
    for (unsigned int i = blockIdx.x*blockDim.x + threadIdx.x; i < cnt;
         i += gridDim.x*blockDim.x) {
        uint2 rec = fixrec[i];
        int n = (int)rec.x;
        int cell = (int)(rec.y >> 8);
        int oc = (int)(rec.y & 255u);
        int py = cell / 14, px = cell % 14;
        float thr = t1[oc];
        double best = -1e300;
        #pragma unroll 1
        for (int d2 = 0; d2 < 4; ++d2) {
            int oy = 2*py + (d2 >> 1), ox = 2*px + (d2 & 1);
            double s = 0.0;
            #pragma unroll 1
            for (int c2 = 0; c2 < 3; ++c2)
                #pragma unroll 1
                for (int ky2 = 0; ky2 < 5; ++ky2)
                    #pragma unroll 1
                    for (int kx2 = 0; kx2 < 5; ++kx2) {
                        float wv = w1[oc*75 + c2*25 + ky2*5 + kx2];
                        float xv = x[(size_t)n*3072 + c2*1024 + (oy + ky2)*32 + ox + kx2];
                        s += (wv > 0.0f) ? (double)xv : -(double)xv;
                    }
            best = fmax(best, s);
        }
        unsigned int mask = 1u << ((cell & 1)*16 + oc);
        unsigned int* wp = &a1u[(size_t)n*98 + (cell >> 1)];
        if (best > (double)thr) atomicOr(wp, mask);
        else                    atomicAnd(wp, ~mask);
    }
}

// ---------------------------------------------------------------------------
// Kernel B (fused): conv2 (xor/popc, pair-packed taps) + pool + sign -> LDS
// masks, then conv3+fc1+fc2+fc3+log_softmax. 1024 blocks x 256 thr,
// 8 images per block (single pass).
// ---------------------------------------------------------------------------
__global__ __launch_bounds__(256) void conv2tail_kernel(
    const unsigned int* __restrict__ a1u, const unsigned int* __restrict__ w2m,
    const float* __restrict__ t2,
    const unsigned int* __restrict__ w3m, const float* __restrict__ t3,
    const unsigned long long* __restrict__ fw1m, const float* __restrict__ tc1,
    const unsigned long long* __restrict__ fw2m, const float* __restrict__ tc2,
    const unsigned long long* __restrict__ fw3m,
    const float* __restrict__ cm3, const float* __restrict__ cv3,
    float* __restrict__ out)
{
    __shared__ unsigned int M[8][14][16];
    __shared__ unsigned int P[8][14][16];
    __shared__ unsigned int Q[8][13][16];
    __shared__ unsigned int a2l[8][25];
    __shared__ unsigned int w3s[1600];
    __shared__ unsigned long long fw1s[128], fw2s[256], fw3s[20];
    __shared__ float t3s[64], tc1s[128], tc2s[128], cm3s[16], cv3s[16];

    const int tid = threadIdx.x;
    const int lane = tid & 63;
    const int wv = tid >> 6;
    const int n0 = blockIdx.x * 8;

    // ---- stage tail weights ----
    for (int i = tid; i < 1600; i += 256) w3s[i] = w3m[i];
    if (tid < 128) { fw1s[tid] = fw1m[tid]; tc1s[tid] = tc1[tid]; tc2s[tid] = tc2[tid]; }
    fw2s[tid] = fw2m[tid];
    if (tid < 20) fw3s[tid] = fw3m[tid];
    if (tid < 64) t3s[tid] = t3[tid];
    if (tid < 10) { cm3s[tid] = cm3[tid]; cv3s[tid] = cv3[tid]; }

    // ---- stage a1 masks ----
    for (int i = tid; i < 8*98; i += 256) {
        unsigned int v = a1u[(size_t)n0*98 + i];
        int e = 2*i;
        int im = e / 196, r = e - im*196;
        int y0 = r / 14, c0 = r - y0*14;
        int r1 = r + 1, y1 = r1 / 14, c1 = r1 - y1*14;
        M[im][y0][c0] = v & 0xffffu;
        M[im][y1][c1] = v >> 16;
    }
    __syncthreads();
    for (int i = tid; i < 8*14*13; i += 256) {
        int im = i / 182, r = i - im*182, y = r / 13, j = r - y*13;
        P[im][y][j] = M[im][y][j] | (M[im][y][j+1] << 16);
    }
    for (int i = tid; i < 8*13*14; i += 256) {
        int im = i / 182, r = i - im*182, y = r / 14, j = r - y*14;
        Q[im][y][j] = M[im][y][j] | (M[im][y+1][j] << 16);
    }
    __syncthreads();

    // ---- conv2 + pool + sign ----
    const int img = tid >> 5, oc = tid & 31;
    unsigned int wrow[25];
    #pragma unroll
    for (int k = 0; k < 25; ++k) wrow[k] = w2m[oc*25 + k];
    unsigned int wp[5][2], wc0, wc1, wcs;
    #pragma unroll
    for (int ky = 0; ky < 5; ++ky) {
        wp[ky][0] = wrow[ky*5]     | (wrow[ky*5+1] << 16);
        wp[ky][1] = wrow[ky*5 + 2] | (wrow[ky*5+3] << 16);
    }
    wc0 = wrow[4]  | (wrow[9]  << 16);
    wc1 = wrow[14] | (wrow[19] << 16);
    wcs = wrow[24];
    const float thr = t2[oc];

    unsigned int bits = 0;
    int hprev[5];
    #pragma unroll 2
    for (int oy = 0; oy < 10; ++oy) {
        unsigned int Pr[5][12];
        #pragma unroll
        for (int ky = 0; ky < 5; ++ky) {
            const uint4* pr = (const uint4*)&P[img][oy + ky][0];
            uint4 a = pr[0], b = pr[1], c = pr[2];
            Pr[ky][0]=a.x; Pr[ky][1]=a.y; Pr[ky][2]=a.z; Pr[ky][3]=a.w;
            Pr[ky][4]=b.x; Pr[ky][5]=b.y; Pr[ky][6]=b.z; Pr[ky][7]=b.w;
            Pr[ky][8]=c.x; Pr[ky][9]=c.y; Pr[ky][10]=c.z; Pr[ky][11]=c.w;
        }
        unsigned int Qa[10], Qb[10], Ms[10];
        {
            const uint4* qa = (const uint4*)&Q[img][oy][4];
            const uint2* qa2 = (const uint2*)&Q[img][oy][12];
            uint4 a = qa[0], b = qa[1]; uint2 c = qa2[0];
            Qa[0]=a.x; Qa[1]=a.y; Qa[2]=a.z; Qa[3]=a.w;
            Qa[4]=b.x; Qa[5]=b.y; Qa[6]=b.z; Qa[7]=b.w; Qa[8]=c.x; Qa[9]=c.y;
            const uint4* qb = (const uint4*)&Q[img][oy+2][4];
            const uint2* qb2 = (const uint2*)&Q[img][oy+2][12];
            uint4 d = qb[0], e = qb[1]; uint2 f = qb2[0];
            Qb[0]=d.x; Qb[1]=d.y; Qb[2]=d.z; Qb[3]=d.w;
            Qb[4]=e.x; Qb[5]=e.y; Qb[6]=e.z; Qb[7]=e.w; Qb[8]=f.x; Qb[9]=f.y;
            const uint4* ms = (const uint4*)&M[img][oy+4][4];
            const uint2* ms2 = (const uint2*)&M[img][oy+4][12];
            uint4 g = ms[0], h = ms[1]; uint2 k2 = ms2[0];
            Ms[0]=g.x; Ms[1]=g.y; Ms[2]=g.z; Ms[3]=g.w;
            Ms[4]=h.x; Ms[5]=h.y; Ms[6]=h.z; Ms[7]=h.w; Ms[8]=k2.x; Ms[9]=k2.y;
        }
        int X[10];
        #pragma unroll
        for (int ox = 0; ox < 10; ++ox) {
            int s = 0;
            #pragma unroll
            for (int ky = 0; ky < 5; ++ky)
                s += __popc(Pr[ky][ox] ^ wp[ky][0]) + __popc(Pr[ky][ox+2] ^ wp[ky][1]);
            s += __popc(Qa[ox] ^ wc0) + __popc(Qb[ox] ^ wc1) + __popc(Ms[ox] ^ wcs);
            X[ox] = s;
        }
        #pragma unroll
        for (int px = 0; px < 5; ++px) {
            int h = min(X[2*px], X[2*px+1]);
            if ((oy & 1) == 0) hprev[px] = h;
            else {
                int mn = min(hprev[px], h);
                if ((float)(400 - 2*mn) > thr) bits |= 1u << ((oy >> 1)*5 + px);
            }
        }
    }
    #pragma unroll
    for (int cell = 0; cell < 25; ++cell) {
        unsigned long long m = __ballot((bits >> cell) & 1);
        if (lane == 0)  a2l[2*wv][cell]     = (unsigned int)m;
        if (lane == 32) a2l[2*wv + 1][cell] = (unsigned int)(m >> 32);
    }
    __syncthreads();

    // ---- tail: 2 rounds x 4 waves = 8 images ----
    #pragma unroll 1
    for (int rnd = 0; rnd < 2; ++rnd) {
        const int im = wv + 4*rnd;
        const int n = n0 + im;

        unsigned int av[25];
        #pragma unroll
        for (int k = 0; k < 25; ++k) av[k] = a2l[im][k];

        int X = 0;
        #pragma unroll
        for (int k = 0; k < 25; ++k) X += __popc(av[k] ^ w3s[lane*25 + k]);
        float d3 = (float)(800 - 2*X);
        unsigned long long a3 = __ballot(d3 > t3s[lane]);

        int o1 = lane + 64;
        int d0 = 64 - 2*(int)__popcll(a3 ^ fw1s[lane]);
        int d1 = 64 - 2*(int)__popcll(a3 ^ fw1s[o1]);
        unsigned long long a4lo = __ballot((float)d0 > tc1s[lane]);
        unsigned long long a4hi = __ballot((float)d1 > tc1s[o1]);

        int e0 = 128 - 2*(int)(__popcll(a4lo ^ fw2s[2*lane]) + __popcll(a4hi ^ fw2s[2*lane+1]));
        int e1 = 128 - 2*(int)(__popcll(a4lo ^ fw2s[2*o1])   + __popcll(a4hi ^ fw2s[2*o1+1]));
        unsigned long long a5lo = __ballot((float)e0 > tc2s[lane]);
        unsigned long long a5hi = __ballot((float)e1 > tc2s[o1]);

        float y = -1e30f;
        if (lane < 10) {
            int f = 128 - 2*(int)(__popcll(a5lo ^ fw3s[2*lane]) + __popcll(a5hi ^ fw3s[2*lane+1]));
            y = ((float)f - cm3s[lane]) / sqrtf(cv3s[lane] + EPS);
        }
        float mx = y;
        #pragma unroll
        for (int off = 8; off > 0; off >>= 1) mx = fmaxf(mx, __shfl_xor(mx, off, 16));
        float s = (lane < 10) ? expf(y - mx) : 0.0f;
        #pragma unroll
        for (int off = 8; off > 0; off >>= 1) s += __shfl_xor(s, off, 16);
        if (lane < 10) out[(size_t)n*10 + lane] = y - mx - logf(s);
    }
}

// ---------------------------------------------------------------------------
extern "C" void kernel_launch(void* const* d_in, const int* in_sizes, int n_in,
                              void* d_out, int out_size, void* d_ws, size_t ws_size,
                              hipStream_t stream)
{
    const float* x   = (const float*)d_in[0];
    const float* w1  = (const float*)d_in[1];
    const float* b1  = (const float*)d_in[2];
    const float* g1  = (const float*)d_in[3];
    const float* be1 = (const float*)d_in[4];
    const float* m1  = (const float*)d_in[5];
    const float* v1  = (const float*)d_in[6];
    const float* w2  = (const float*)d_in[7];
    const float* b2  = (const float*)d_in[8];
    const float* g2  = (const float*)d_in[9];
    const float* be2 = (const float*)d_in[10];
    const float* m2  = (const float*)d_in[11];
    const float* v2  = (const float*)d_in[12];
    const float* w3  = (const float*)d_in[13];
    const float* b3  = (const float*)d_in[14];
    const float* g3  = (const float*)d_in[15];
    const float* be3 = (const float*)d_in[16];
    const float* m3  = (const float*)d_in[17];
    const float* v3  = (const float*)d_in[18];
    const float* fw1 = (const float*)d_in[19];
    const float* fb1 = (const float*)d_in[20];
    const float* cm1 = (const float*)d_in[21];
    const float* fw2 = (const float*)d_in[23];
    const float* fb2 = (const float*)d_in[24];
    const float* cm2 = (const float*)d_in[25];
    const float* fw3 = (const float*)d_in[27];
    const float* cm3 = (const float*)d_in[28];
    const float* cv3 = (const float*)d_in[29];

    char* ws = (char*)d_ws;
    unsigned int*       a1u  = (unsigned int*)(ws + A1_OFF);
    unsigned int*       w2m  = (unsigned int*)(ws + W2M_OFF);
    unsigned int*       w3m  = (unsigned int*)(ws + W3M_OFF);
    unsigned long long* fw1m = (unsigned long long*)(ws + FW1M_OFF);
    unsigned long long* fw2m = (unsigned long long*)(ws + FW2M_OFF);
    unsigned long long* fw3m = (unsigned long long*)(ws + FW3M_OFF);
    float* t1  = (float*)(ws + T1_OFF);
    float* t2  = (float*)(ws + T2_OFF);
    float* t3  = (float*)(ws + T3_OFF);
    float* tc1 = (float*)(ws + TC1_OFF);
    float* tc2 = (float*)(ws + TC2_OFF);
    uint4* bfrag = (uint4*)(ws + BF_OFF);
    unsigned int* fixcnt = (unsigned int*)(ws + FIXCNT_OFF);
    uint2* fixrec = (uint2*)(ws + FIXREC_OFF);

    setup_kernel<<<5, 256, 0, stream>>>(
        w1, w2, w3, fw1, fw2, fw3,
        b1, g1, be1, m1, v1,
        b2, g2, be2, m2, v2,
        b3, g3, be3, m3, v3,
        fb1, cm1, fb2, cm2,
        w2m, w3m, fw1m, fw2m, fw3m, t1, t2, t3, tc1, tc2, bfrag, fixcnt);

    convpool1_kernel<<<1024, 256, 0, stream>>>(x, t1, bfrag, a1u, fixcnt, fixrec);
    fixup_kernel<<<64, 256, 0, stream>>>(x, w1, t1, fixcnt, fixrec, a1u);
    conv2tail_kernel<<<1024, 256, 0, stream>>>(a1u, w2m, t2, w3m, t3,
                                               fw1m, tc1, fw2m, tc2, fw3m,
                                               cm3, cv3, (float*)d_out);
}

// Round 7
// 329.329 us; speedup vs baseline: 1.5392x; 1.0402x over previous
//
#include <hip/hip_runtime.h>
#include <cstdint>

#define EPS 1e-5f

// ---- workspace layout (bytes) ----
#define A1_OFF   0ull                 // 8192*98 u32 (a1 bitmasks, 16 ch, py*14+px pairs)
#define W2M_OFF  4030464ull           // 32*25 u32
#define W3M_OFF  4033664ull           // 64*25 u32
#define FW1M_OFF 4040064ull           // 128 u64
#define FW2M_OFF 4041088ull           // 128*2 u64
#define FW3M_OFF 4043136ull           // 10*2 u64
#define T1_OFF   4043296ull           // 16 f32
#define T2_OFF   4043360ull           // 32 f32
#define T3_OFF   4043488ull           // 64 f32
#define TC1_OFF  4043744ull           // 128 f32
#define TC2_OFF  4044256ull           // 128 f32
#define BF_OFF   4044768ull           // 4dlt*4kg*64lane uint4 = 16KB (conv1 B-fragments)
#define FIXCNT_OFF 4061184ull         // 1 u32
#define FIXREC_OFF 4061248ull         // 32768 uint2 = 256KB
#define FIXCAP   32768u

using bf16x8 = __attribute__((ext_vector_type(8))) short;
using f32x4  = __attribute__((ext_vector_type(4))) float;

union FragU { unsigned int u[4]; bf16x8 f; };

__device__ inline unsigned short rne_bf16(float f) {
    unsigned int u = __float_as_uint(f);
    return (unsigned short)((u + 0x7FFFu + ((u >> 16) & 1u)) >> 16);
}

// ---------------------------------------------------------------------------
// Setup (grid=5): pack binarized weights to bitmasks, fold bn+bias into
// thresholds, build conv1 MFMA B-fragments, zero the fixup counter.
// ---------------------------------------------------------------------------
__global__ void setup_kernel(
    const float* __restrict__ w1, const float* __restrict__ w2,
    const float* __restrict__ w3,
    const float* __restrict__ fw1, const float* __restrict__ fw2,
    const float* __restrict__ fw3,
    const float* __restrict__ b1, const float* __restrict__ g1,
    const float* __restrict__ be1, const float* __restrict__ m1,
    const float* __restrict__ v1,
    const float* __restrict__ b2, const float* __restrict__ g2,
    const float* __restrict__ be2, const float* __restrict__ m2,
    const float* __restrict__ v2,
    const float* __restrict__ b3, const float* __restrict__ g3,
    const float* __restrict__ be3, const float* __restrict__ m3,
    const float* __restrict__ v3,
    const float* __restrict__ fb1, const float* __restrict__ cm1,
    const float* __restrict__ fb2, const float* __restrict__ cm2,
    unsigned int* __restrict__ w2m, unsigned int* __restrict__ w3m,
    unsigned long long* __restrict__ fw1m, unsigned long long* __restrict__ fw2m,
    unsigned long long* __restrict__ fw3m,
    float* __restrict__ t1, float* __restrict__ t2, float* __restrict__ t3,
    float* __restrict__ tc1, float* __restrict__ tc2,
    uint4* __restrict__ bfrag, unsigned int* __restrict__ fixcnt)
{
    const int tid = threadIdx.x;
    const int blk = blockIdx.x;

    if (blk == 0) {
        if (tid < 16) t1[tid] = m1[tid] - be1[tid]*sqrtf(v1[tid]+EPS)/g1[tid] - b1[tid];
        if (tid < 32) t2[tid] = m2[tid] - be2[tid]*sqrtf(v2[tid]+EPS)/g2[tid] - b2[tid];
        if (tid < 64) t3[tid] = m3[tid] - be3[tid]*sqrtf(v3[tid]+EPS)/g3[tid] - b3[tid];
        if (tid < 128) { tc1[tid] = cm1[tid] - fb1[tid]; tc2[tid] = cm2[tid] - fb2[tid]; }
        for (int t = tid; t < 32*25; t += 256) {        // w2: (32,16,5,5)
            int oc = t / 25, pos = t % 25;
            unsigned int mk = 0;
            for (int ic = 0; ic < 16; ++ic)
                if (w2[(oc*16 + ic)*25 + pos] > 0.0f) mk |= 1u << ic;
            w2m[t] = mk;
        }
    } else if (blk == 1) {
        for (int t = tid; t < 64*25; t += 256) {        // w3: (64,32,5,5)
            int oc = t / 25, pos = t % 25;
            unsigned int mk = 0;
            for (int ic = 0; ic < 32; ++ic)
                if (w3[(oc*32 + ic)*25 + pos] > 0.0f) mk |= 1u << ic;
            w3m[t] = mk;
        }
    } else if (blk == 2) {
        for (int t = tid; t < 128; t += 256) {          // fw1: (128,64)
            unsigned long long mk = 0;
            for (int i = 0; i < 64; ++i)
                if (fw1[t*64 + i] > 0.0f) mk |= 1ull << i;
            fw1m[t] = mk;
        }
    } else if (blk == 3) {
        for (int t = tid; t < 128; t += 256) {          // fw2: (128,128)
            unsigned long long lo = 0, hi = 0;
            for (int i = 0; i < 64; ++i) {
                if (fw2[t*128 + i]      > 0.0f) lo |= 1ull << i;
                if (fw2[t*128 + 64 + i] > 0.0f) hi |= 1ull << i;
            }
            fw2m[2*t] = lo; fw2m[2*t+1] = hi;
        }
        if (tid < 10) {                                  // fw3: (10,128)
            unsigned long long lo = 0, hi = 0;
            for (int i = 0; i < 64; ++i) {
                if (fw3[tid*128 + i]      > 0.0f) lo |= 1ull << i;
                if (fw3[tid*128 + 64 + i] > 0.0f) hi |= 1ull << i;
            }
            fw3m[2*tid] = lo; fw3m[2*tid+1] = hi;
        }
    } else {
        if (tid == 0) fixcnt[0] = 0;
        // conv1 B-fragments. B-operand of 16x16x32 bf16 MFMA:
        // n = lane&15 (oc), k = (lane>>4)*8 + j; ck = kg*4 + (lane>>4),
        // kx = j - delta.
        if (tid < 64) {
            const int oc = tid & 15, q = tid >> 4;
            for (int d = 0; d < 4; ++d)
                for (int kg = 0; kg < 4; ++kg) {
                    int ck = kg*4 + q;
                    unsigned short s[8];
                    for (int j = 0; j < 8; ++j) {
                        int kx = j - d;
                        unsigned short v = 0;
                        if (ck < 15 && kx >= 0 && kx < 5)
                            v = (w1[oc*75 + ck*5 + kx] > 0.0f) ? 0x3F80 : 0xBF80;
                        s[j] = v;
                    }
                    uint4 o;
                    o.x = (unsigned int)s[0] | ((unsigned int)s[1] << 16);
                    o.y = (unsigned int)s[2] | ((unsigned int)s[3] << 16);
                    o.z = (unsigned int)s[4] | ((unsigned int)s[5] << 16);
                    o.w = (unsigned int)s[6] | ((unsigned int)s[7] << 16);
                    bfrag[(d*4 + kg)*64 + tid] = o;
                }
        }
    }
}

// ---------------------------------------------------------------------------
// Kernel A (MFMA): conv1 + pool + sign -> packed u32 masks.
// 2048 blocks x 128 thr (2 waves); each block: 4 images.  Per image 14 tasks
// = (ox-group g 0..6) x (oy-tile tt 0/1); wave w does tasks w*7..w*7+6 --
// perfectly balanced (the R6 4-wave split was 4/4/3/3).  Task: A-frag
// 16 oy-rows x 8 cols from LDS, reused by 4 MFMAs with kx-shifted B
// variants (delta -> ox = 4g+delta).  bf16 hi+lo passes accumulate fp32.
// Near-threshold cells (|h-thr|<2e-3, rigorous bound ~1.5e-3) go to a
// global fixup list; NO calls in the hot loop (noinline call caused the
// B-array scratch spill that poisoned R3-R5).  Staging is direct
// (global->convert->LDS) in the store phase; ~6 co-resident 2-wave blocks
// per CU hide the latency.
// ---------------------------------------------------------------------------
__global__ __launch_bounds__(128) void convpool1_kernel(
    const float* __restrict__ x, const float* __restrict__ t1,
    const uint4* __restrict__ bfrag, unsigned int* __restrict__ a1u,
    unsigned int* __restrict__ fixcnt, uint2* __restrict__ fixrec)
{
    __shared__ alignas(16) unsigned short xh[3*36*44];
    __shared__ alignas(16) unsigned short xl[3*36*44];
    __shared__ unsigned short pk16[196];

    const int tid  = threadIdx.x;
    const int lane = tid & 63;
    const int wv   = tid >> 6;        // wave 0..1
    const int quad = lane >> 4;
    const int me   = lane & 15;
    const int n0   = blockIdx.x * 4;

    FragU B[16];
    #pragma unroll
    for (int i = 0; i < 16; ++i)
        *(uint4*)B[i].u = bfrag[i*64 + lane];

    // per-kg LDS row base (constant across images/tasks)
    int basekg[4];
    #pragma unroll
    for (int kg = 0; kg < 4; ++kg) {
        int ck = kg*4 + quad;
        int ckc = ck < 15 ? ck : 14;               // ck==15 -> zero B
        int c = ckc / 5, ky = ckc % 5;
        basekg[kg] = (c*36 + ky + me)*44;
    }
    // staging element indices (constant): j = tid + k*128, k=0..5
    int se[6];
    #pragma unroll
    for (int k = 0; k < 6; ++k) {
        int j = tid + k*128;
        int c = j >> 8, f = j & 255, row = f >> 3, q = f & 7;
        se[k] = (c*36 + row)*44 + 4*q;
    }

    const float thr = t1[me];
    #pragma unroll 1
    for (int i = 0; i < 4; ++i) {
        // ---- store phase: a1u for image i-1, stage image i ----
        if (i > 0 && tid < 98)
            a1u[(size_t)(n0 + i - 1)*98 + tid] =
                (unsigned int)pk16[2*tid] | ((unsigned int)pk16[2*tid + 1] << 16);
        {
            const float4* xg = (const float4*)(x + (size_t)(n0 + i) * 3072);
            float4 v[6];
            #pragma unroll
            for (int k = 0; k < 6; ++k) v[k] = xg[tid + k*128];
            #pragma unroll
            for (int k = 0; k < 6; ++k) {
                unsigned short h0 = rne_bf16(v[k].x), h1 = rne_bf16(v[k].y),
                               h2 = rne_bf16(v[k].z), h3 = rne_bf16(v[k].w);
                float r0 = v[k].x - __uint_as_float((unsigned int)h0 << 16);
                float r1 = v[k].y - __uint_as_float((unsigned int)h1 << 16);
                float r2 = v[k].z - __uint_as_float((unsigned int)h2 << 16);
                float r3 = v[k].w - __uint_as_float((unsigned int)h3 << 16);
                uint2 ph, pl;
                ph.x = (unsigned int)h0 | ((unsigned int)h1 << 16);
                ph.y = (unsigned int)h2 | ((unsigned int)h3 << 16);
                pl.x = (unsigned int)rne_bf16(r0) | ((unsigned int)rne_bf16(r1) << 16);
                pl.y = (unsigned int)rne_bf16(r2) | ((unsigned int)rne_bf16(r3) << 16);
                *(uint2*)&xh[se[k]] = ph;
                *(uint2*)&xl[se[k]] = pl;
            }
        }
        __syncthreads();

        // ---- compute image i: 7 tasks per wave ----
        const int n = n0 + i;
        #pragma unroll 1
        for (int ti = 0; ti < 7; ++ti) {
            const int task = wv*7 + ti;
            const int g = task >> 1, tt = task & 1;
            const int off = 4*g + tt*704;          // wave-uniform

            f32x4 acc[4];
            #pragma unroll
            for (int d = 0; d < 4; ++d) acc[d] = (f32x4){0.f, 0.f, 0.f, 0.f};

            #pragma unroll
            for (int kg = 0; kg < 4; ++kg) {
                int idx = basekg[kg] + off;
                FragU ah, al;
                uint2 p0 = *(const uint2*)&xh[idx];
                uint2 p1 = *(const uint2*)&xh[idx + 4];
                ah.u[0] = p0.x; ah.u[1] = p0.y; ah.u[2] = p1.x; ah.u[3] = p1.y;
                uint2 q0 = *(const uint2*)&xl[idx];
                uint2 q1 = *(const uint2*)&xl[idx + 4];
                al.u[0] = q0.x; al.u[1] = q0.y; al.u[2] = q1.x; al.u[3] = q1.y;
                #pragma unroll
                for (int d = 0; d < 4; ++d)
                    acc[d] = __builtin_amdgcn_mfma_f32_16x16x32_bf16(
                        ah.f, B[d*4 + kg].f, acc[d], 0, 0, 0);
                #pragma unroll
                for (int d = 0; d < 4; ++d)
                    acc[d] = __builtin_amdgcn_mfma_f32_16x16x32_bf16(
                        al.f, B[d*4 + kg].f, acc[d], 0, 0, 0);
            }

            // pool + sign + pack. Lane: oc=me (C col), C row = quad*4+reg.
            const int valid = !(tt == 1 && quad == 3);   // py 14,15 discarded
            #pragma unroll
            for (int dp = 0; dp < 2; ++dp) {
                f32x4 A0 = acc[2*dp], A1 = acc[2*dp + 1];
                #pragma unroll
                for (int r = 0; r < 2; ++r) {
                    float h = fmaxf(fmaxf(A0[2*r], A0[2*r+1]),
                                    fmaxf(A1[2*r], A1[2*r+1]));
                    int bit = h > thr;
                    if (valid && fabsf(h - thr) < 2e-3f) {
                        int cell = (tt*8 + quad*2 + r)*14 + 2*g + dp;
                        unsigned int slot = atomicAdd(fixcnt, 1u);
                        if (slot < FIXCAP) {
                            uint2 rec;
                            rec.x = (unsigned int)n;
                            rec.y = ((unsigned int)cell << 8) | (unsigned int)me;
                            fixrec[slot] = rec;
                        }
                    }
                    unsigned long long mk = __ballot(bit);
                    if (me == 0 && valid)
                        pk16[(tt*8 + quad*2 + r)*14 + 2*g + dp] =
                            (unsigned short)(mk >> (quad*16));
                }
            }
        }
        __syncthreads();
    }
    // epilogue: image 3 masks
    if (tid < 98)
        a1u[(size_t)(n0 + 3)*98 + tid] =
            (unsigned int)pk16[2*tid] | ((unsigned int)pk16[2*tid + 1] << 16);
}

// ---------------------------------------------------------------------------
// Fixup: exact fp64 recompute of near-threshold pooled cells; patch a1u bits.
// ---------------------------------------------------------------------------
__global__ void fixup_kernel(
    const float* __restrict__ x, const float* __restrict__ w1,
    const float* __restrict__ t1,
    const unsigned int* __restrict__ fixcnt, const uint2* __restrict__ fixrec,
    unsigned int* __restrict__ a1u)
{
    unsigned int cnt = fixcnt[0];
    if (cnt > FIXCAP) cnt = FIXCAP;
    for (unsigned int i = blockIdx.x*blockDim.x + threadIdx.x; i < cnt;
         i += gridDim.x*blockDim.x) {
        uint2 rec = fixrec[i];
        int n = (int)rec.x;
        int cell = (int)(rec.y >> 8);
        int oc = (int)(rec.y & 255u);
        int py = cell / 14, px = cell % 14;
        float thr = t1[oc];
        double best = -1e300;
        #pragma unroll 1
        for (int d2 = 0; d2 < 4; ++d2) {
            int oy = 2*py + (d2 >> 1), ox = 2*px + (d2 & 1);
            double s = 0.0;
            #pragma unroll 1
            for (int c2 = 0; c2 < 3; ++c2)
                #pragma unroll 1
                for (int ky2 = 0; ky2 < 5; ++ky2)
                    #pragma unroll 1
                    for (int kx2 = 0; kx2 < 5; ++kx2) {
                        float wv = w1[oc*75 + c2*25 + ky2*5 + kx2];
                        float xv = x[(size_t)n*3072 + c2*1024 + (oy + ky2)*32 + ox + kx2];
                        s += (wv > 0.0f) ? (double)xv : -(double)xv;
                    }
            best = fmax(best, s);
        }
        unsigned int mask = 1u << ((cell & 1)*16 + oc);
        unsigned int* wp = &a1u[(size_t)n*98 + (cell >> 1)];
        if (best > (double)thr) atomicOr(wp, mask);
        else                    atomicAnd(wp, ~mask);
    }
}

// ---------------------------------------------------------------------------
// Kernel B (fused): conv2 (xor/popc, pair-packed taps) + pool + sign -> LDS
// masks, then conv3+fc1+fc2+fc3+log_softmax. 1024 blocks x 256 thr,
// 8 images per block (single pass).
// ---------------------------------------------------------------------------
__global__ __launch_bounds__(256) void conv2tail_kernel(
    const unsigned int* __restrict__ a1u, const unsigned int* __restrict__ w2m,
    const float* __restrict__ t2,
    const unsigned int* __restrict__ w3m, const float* __restrict__ t3,
    const unsigned long long* __restrict__ fw1m, const float* __restrict__ tc1,
    const unsigned long long* __restrict__ fw2m, const float* __restrict__ tc2,
    const unsigned long long* __restrict__ fw3m,
    const float* __restrict__ cm3, const float* __restrict__ cv3,
    float* __restrict__ out)
{
    __shared__ unsigned int M[8][14][16];
    __shared__ unsigned int P[8][14][16];
    __shared__ unsigned int Q[8][13][16];
    __shared__ unsigned int a2l[8][25];
    __shared__ unsigned int w3s[1600];
    __shared__ unsigned long long fw1s[128], fw2s[256], fw3s[20];
    __shared__ float t3s[64], tc1s[128], tc2s[128], cm3s[16], cv3s[16];

    const int tid = threadIdx.x;
    const int lane = tid & 63;
    const int wv = tid >> 6;
    const int n0 = blockIdx.x * 8;

    // ---- stage tail weights ----
    for (int i = tid; i < 1600; i += 256) w3s[i] = w3m[i];
    if (tid < 128) { fw1s[tid] = fw1m[tid]; tc1s[tid] = tc1[tid]; tc2s[tid] = tc2[tid]; }
    fw2s[tid] = fw2m[tid];
    if (tid < 20) fw3s[tid] = fw3m[tid];
    if (tid < 64) t3s[tid] = t3[tid];
    if (tid < 10) { cm3s[tid] = cm3[tid]; cv3s[tid] = cv3[tid]; }

    // ---- stage a1 masks ----
    for (int i = tid; i < 8*98; i += 256) {
        unsigned int v = a1u[(size_t)n0*98 + i];
        int e = 2*i;
        int im = e / 196, r = e - im*196;
        int y0 = r / 14, c0 = r - y0*14;
        int r1 = r + 1, y1 = r1 / 14, c1 = r1 - y1*14;
        M[im][y0][c0] = v & 0xffffu;
        M[im][y1][c1] = v >> 16;
    }
    __syncthreads();
    for (int i = tid; i < 8*14*13; i += 256) {
        int im = i / 182, r = i - im*182, y = r / 13, j = r - y*13;
        P[im][y][j] = M[im][y][j] | (M[im][y][j+1] << 16);
    }
    for (int i = tid; i < 8*13*14; i += 256) {
        int im = i / 182, r = i - im*182, y = r / 14, j = r - y*14;
        Q[im][y][j] = M[im][y][j] | (M[im][y+1][j] << 16);
    }
    __syncthreads();

    // ---- conv2 + pool + sign ----
    const int img = tid >> 5, oc = tid & 31;
    unsigned int wrow[25];
    #pragma unroll
    for (int k = 0; k < 25; ++k) wrow[k] = w2m[oc*25 + k];
    unsigned int wp[5][2], wc0, wc1, wcs;
    #pragma unroll
    for (int ky = 0; ky < 5; ++ky) {
        wp[ky][0] = wrow[ky*5]     | (wrow[ky*5+1] << 16);
        wp[ky][1] = wrow[ky*5 + 2] | (wrow[ky*5+3] << 16);
    }
    wc0 = wrow[4]  | (wrow[9]  << 16);
    wc1 = wrow[14] | (wrow[19] << 16);
    wcs = wrow[24];
    const float thr = t2[oc];

    unsigned int bits = 0;
    int hprev[5];
    #pragma unroll 2
    for (int oy = 0; oy < 10; ++oy) {
        unsigned int Pr[5][12];
        #pragma unroll
        for (int ky = 0; ky < 5; ++ky) {
            const uint4* pr = (const uint4*)&P[img][oy + ky][0];
            uint4 a = pr[0], b = pr[1], c = pr[2];
            Pr[ky][0]=a.x; Pr[ky][1]=a.y; Pr[ky][2]=a.z; Pr[ky][3]=a.w;
            Pr[ky][4]=b.x; Pr[ky][5]=b.y; Pr[ky][6]=b.z; Pr[ky][7]=b.w;
            Pr[ky][8]=c.x; Pr[ky][9]=c.y; Pr[ky][10]=c.z; Pr[ky][11]=c.w;
        }
        unsigned int Qa[10], Qb[10], Ms[10];
        {
            const uint4* qa = (const uint4*)&Q[img][oy][4];
            const uint2* qa2 = (const uint2*)&Q[img][oy][12];
            uint4 a = qa[0], b = qa[1]; uint2 c = qa2[0];
            Qa[0]=a.x; Qa[1]=a.y; Qa[2]=a.z; Qa[3]=a.w;
            Qa[4]=b.x; Qa[5]=b.y; Qa[6]=b.z; Qa[7]=b.w; Qa[8]=c.x; Qa[9]=c.y;
            const uint4* qb = (const uint4*)&Q[img][oy+2][4];
            const uint2* qb2 = (const uint2*)&Q[img][oy+2][12];
            uint4 d = qb[0], e = qb[1]; uint2 f = qb2[0];
            Qb[0]=d.x; Qb[1]=d.y; Qb[2]=d.z; Qb[3]=d.w;
            Qb[4]=e.x; Qb[5]=e.y; Qb[6]=e.z; Qb[7]=e.w; Qb[8]=f.x; Qb[9]=f.y;
            const uint4* ms = (const uint4*)&M[img][oy+4][4];
            const uint2* ms2 = (const uint2*)&M[img][oy+4][12];
            uint4 g = ms[0], h = ms[1]; uint2 k2 = ms2[0];
            Ms[0]=g.x; Ms[1]=g.y; Ms[2]=g.z; Ms[3]=g.w;
            Ms[4]=h.x; Ms[5]=h.y; Ms[6]=h.z; Ms[7]=h.w; Ms[8]=k2.x; Ms[9]=k2.y;
        }
        int X[10];
        #pragma unroll
        for (int ox = 0; ox < 10; ++ox) {
            int s = 0;
            #pragma unroll
            for (int ky = 0; ky < 5; ++ky)
                s += __popc(Pr[ky][ox] ^ wp[ky][0]) + __popc(Pr[ky][ox+2] ^ wp[ky][1]);
            s += __popc(Qa[ox] ^ wc0) + __popc(Qb[ox] ^ wc1) + __popc(Ms[ox] ^ wcs);
            X[ox] = s;
        }
        #pragma unroll
        for (int px = 0; px < 5; ++px) {
            int h = min(X[2*px], X[2*px+1]);
            if ((oy & 1) == 0) hprev[px] = h;
            else {
                int mn = min(hprev[px], h);
                if ((float)(400 - 2*mn) > thr) bits |= 1u << ((oy >> 1)*5 + px);
            }
        }
    }
    #pragma unroll
    for (int cell = 0; cell < 25; ++cell) {
        unsigned long long m = __ballot((bits >> cell) & 1);
        if (lane == 0)  a2l[2*wv][cell]     = (unsigned int)m;
        if (lane == 32) a2l[2*wv + 1][cell] = (unsigned int)(m >> 32);
    }
    __syncthreads();

    // ---- tail: 2 rounds x 4 waves = 8 images ----
    #pragma unroll 1
    for (int rnd = 0; rnd < 2; ++rnd) {
        const int im = wv + 4*rnd;
        const int n = n0 + im;

        unsigned int av[25];
        #pragma unroll
        for (int k = 0; k < 25; ++k) av[k] = a2l[im][k];

        int X = 0;
        #pragma unroll
        for (int k = 0; k < 25; ++k) X += __popc(av[k] ^ w3s[lane*25 + k]);
        float d3 = (float)(800 - 2*X);
        unsigned long long a3 = __ballot(d3 > t3s[lane]);

        int o1 = lane + 64;
        int d0 = 64 - 2*(int)__popcll(a3 ^ fw1s[lane]);
        int d1 = 64 - 2*(int)__popcll(a3 ^ fw1s[o1]);
        unsigned long long a4lo = __ballot((float)d0 > tc1s[lane]);
        unsigned long long a4hi = __ballot((float)d1 > tc1s[o1]);

        int e0 = 128 - 2*(int)(__popcll(a4lo ^ fw2s[2*lane]) + __popcll(a4hi ^ fw2s[2*lane+1]));
        int e1 = 128 - 2*(int)(__popcll(a4lo ^ fw2s[2*o1])   + __popcll(a4hi ^ fw2s[2*o1+1]));
        unsigned long long a5lo = __ballot((float)e0 > tc2s[lane]);
        unsigned long long a5hi = __ballot((float)e1 > tc2s[o1]);

        float y = -1e30f;
        if (lane < 10) {
            int f = 128 - 2*(int)(__popcll(a5lo ^ fw3s[2*lane]) + __popcll(a5hi ^ fw3s[2*lane+1]));
            y = ((float)f - cm3s[lane]) / sqrtf(cv3s[lane] + EPS);
        }
        float mx = y;
        #pragma unroll
        for (int off = 8; off > 0; off >>= 1) mx = fmaxf(mx, __shfl_xor(mx, off, 16));
        float s = (lane < 10) ? expf(y - mx) : 0.0f;
        #pragma unroll
        for (int off = 8; off > 0; off >>= 1) s += __shfl_xor(s, off, 16);
        if (lane < 10) out[(size_t)n*10 + lane] = y - mx - logf(s);
    }
}

// ---------------------------------------------------------------------------
extern "C" void kernel_launch(void* const* d_in, const int* in_sizes, int n_in,
                              void* d_out, int out_size, void* d_ws, size_t ws_size,
                              hipStream_t stream)
{
    const float* x   = (const float*)d_in[0];
    const float* w1  = (const float*)d_in[1];
    const float* b1  = (const float*)d_in[2];
    const float* g1  = (const float*)d_in[3];
    const float* be1 = (const float*)d_in[4];
    const float* m1  = (const float*)d_in[5];
    const float* v1  = (const float*)d_in[6];
    const float* w2  = (const float*)d_in[7];
    const float* b2  = (const float*)d_in[8];
    const float* g2  = (const float*)d_in[9];
    const float* be2 = (const float*)d_in[10];
    const float* m2  = (const float*)d_in[11];
    const float* v2  = (const float*)d_in[12];
    const float* w3  = (const float*)d_in[13];
    const float* b3  = (const float*)d_in[14];
    const float* g3  = (const float*)d_in[15];
    const float* be3 = (const float*)d_in[16];
    const float* m3  = (const float*)d_in[17];
    const float* v3  = (const float*)d_in[18];
    const float* fw1 = (const float*)d_in[19];
    const float* fb1 = (const float*)d_in[20];
    const float* cm1 = (const float*)d_in[21];
    const float* fw2 = (const float*)d_in[23];
    const float* fb2 = (const float*)d_in[24];
    const float* cm2 = (const float*)d_in[25];
    const float* fw3 = (const float*)d_in[27];
    const float* cm3 = (const float*)d_in[28];
    const float* cv3 = (const float*)d_in[29];

    char* ws = (char*)d_ws;
    unsigned int*       a1u  = (unsigned int*)(ws + A1_OFF);
    unsigned int*       w2m  = (unsigned int*)(ws + W2M_OFF);
    unsigned int*       w3m  = (unsigned int*)(ws + W3M_OFF);
    unsigned long long* fw1m = (unsigned long long*)(ws + FW1M_OFF);
    unsigned long long* fw2m = (unsigned long long*)(ws + FW2M_OFF);
    unsigned long long* fw3m = (unsigned long long*)(ws + FW3M_OFF);
    float* t1  = (float*)(ws + T1_OFF);
    float* t2  = (float*)(ws + T2_OFF);
    float* t3  = (float*)(ws + T3_OFF);
    float* tc1 = (float*)(ws + TC1_OFF);
    float* tc2 = (float*)(ws + TC2_OFF);
    uint4* bfrag = (uint4*)(ws + BF_OFF);
    unsigned int* fixcnt = (unsigned int*)(ws + FIXCNT_OFF);
    uint2* fixrec = (uint2*)(ws + FIXREC_OFF);

    setup_kernel<<<5, 256, 0, stream>>>(
        w1, w2, w3, fw1, fw2, fw3,
        b1, g1, be1, m1, v1,
        b2, g2, be2, m2, v2,
        b3, g3, be3, m3, v3,
        fb1, cm1, fb2, cm2,
        w2m, w3m, fw1m, fw2m, fw3m, t1, t2, t3, tc1, tc2, bfrag, fixcnt);

    convpool1_kernel<<<2048, 128, 0, stream>>>(x, t1, bfrag, a1u, fixcnt, fixrec);
    fixup_kernel<<<64, 256, 0, stream>>>(x, w1, t1, fixcnt, fixrec, a1u);
    conv2tail_kernel<<<1024, 256, 0, stream>>>(a1u, w2m, t2, w3m, t3,
                                               fw1m, tc1, fw2m, tc2, fw3m,
                                               cm3, cv3, (float*)d_out);
}